// Round 1
// baseline (370.148 us; speedup 1.0000x reference)
//
#include <hip/hip_runtime.h>
#include <stdint.h>

#define NPTS      1048576
#define LEVELS    16
#define TSIZE     524288
#define TMASK     (TSIZE - 1)
#define PRIME1    2654435761u

// floor(16 * 2^(l/3)) — canonical instant-NGP resolution ladder for
// N_MIN=16, N_MAX=512, 16 levels (growth b = 2^(1/3)).
__device__ __constant__ float c_res[LEVELS] = {
    16.f, 20.f, 25.f, 32.f, 40.f, 50.f, 64.f, 80.f,
    101.f, 128.f, 161.f, 203.f, 256.f, 322.f, 406.f, 512.f
};

__global__ __launch_bounds__(256)
void hashenc_kernel(const float* __restrict__ x,
                    const float* __restrict__ tables,
                    float* __restrict__ out,
                    int npts) {
    int n = blockIdx.x * 256 + threadIdx.x;
    if (n >= npts) return;

    // coalesced 8B load of the 2D point
    float2 p = reinterpret_cast<const float2*>(x)[n];

    float acc0[LEVELS];  // feature 0 per level
    float acc1[LEVELS];  // feature 1 per level

#pragma unroll
    for (int l = 0; l < LEVELS; ++l) {
        float r  = c_res[l];
        float s0 = p.x * r;
        float s1 = p.y * r;
        float g0 = floorf(s0);
        float g1 = floorf(s1);
        uint32_t i0 = (uint32_t)(int)g0;
        uint32_t i1 = (uint32_t)(int)g1;

        // hash = (cx*1) ^ (cy*2654435761) & mask; corners in _BORDER order:
        // c0=(0,0) c1=(1,0) c2=(0,1) c3=(1,1)
        uint32_t hy0 = i1 * PRIME1;
        uint32_t hy1 = (i1 + 1u) * PRIME1;
        uint32_t h00 = ( i0        ^ hy0) & TMASK;
        uint32_t h10 = ((i0 + 1u)  ^ hy0) & TMASK;
        uint32_t h01 = ( i0        ^ hy1) & TMASK;
        uint32_t h11 = ((i0 + 1u)  ^ hy1) & TMASK;

        const float2* tab = reinterpret_cast<const float2*>(tables) + (size_t)l * TSIZE;
        float2 t00 = tab[h00];
        float2 t10 = tab[h10];
        float2 t01 = tab[h01];
        float2 t11 = tab[h11];

        // weights: |s - corner| product over dims (matches reference exactly)
        float wx0 = fabsf(s0 - g0);
        float wx1 = fabsf(s0 - (g0 + 1.f));
        float wy0 = fabsf(s1 - g1);
        float wy1 = fabsf(s1 - (g1 + 1.f));
        float w00 = wx0 * wy0;
        float w10 = wx1 * wy0;
        float w01 = wx0 * wy1;
        float w11 = wx1 * wy1;

        acc0[l] = w00 * t00.x + w10 * t10.x + w01 * t01.x + w11 * t11.x;
        acc1[l] = w00 * t00.y + w10 * t10.y + w01 * t01.y + w11 * t11.y;
    }

    // out[n][f*16 + l]: feature 0 at offsets 0..15, feature 1 at 16..31.
    // Each thread writes its own 128B line via 8 float4 stores.
    float4* o = reinterpret_cast<float4*>(out + (size_t)n * 32);
    o[0] = make_float4(acc0[0],  acc0[1],  acc0[2],  acc0[3]);
    o[1] = make_float4(acc0[4],  acc0[5],  acc0[6],  acc0[7]);
    o[2] = make_float4(acc0[8],  acc0[9],  acc0[10], acc0[11]);
    o[3] = make_float4(acc0[12], acc0[13], acc0[14], acc0[15]);
    o[4] = make_float4(acc1[0],  acc1[1],  acc1[2],  acc1[3]);
    o[5] = make_float4(acc1[4],  acc1[5],  acc1[6],  acc1[7]);
    o[6] = make_float4(acc1[8],  acc1[9],  acc1[10], acc1[11]);
    o[7] = make_float4(acc1[12], acc1[13], acc1[14], acc1[15]);
}

extern "C" void kernel_launch(void* const* d_in, const int* in_sizes, int n_in,
                              void* d_out, int out_size, void* d_ws, size_t ws_size,
                              hipStream_t stream) {
    const float* x      = (const float*)d_in[0];
    const float* tables = (const float*)d_in[1];
    float* out          = (float*)d_out;
    int npts = in_sizes[0] / 2;  // INPUT_DIM = 2
    int blocks = (npts + 255) / 256;
    hashenc_kernel<<<blocks, 256, 0, stream>>>(x, tables, out, npts);
}